// Round 8
// baseline (1380.900 us; speedup 1.0000x reference)
//
#include <hip/hip_runtime.h>

namespace {
constexpr int kB = 16;
constexpr int kN = 4096;
constexpr int kS = 1024;
constexpr int kK = 32;
constexpr int kCF = 67;   // 3 + 64
constexpr int kSK = kS * kK;      // 32768
constexpr int kPT = kB * kSK;     // 524288
constexpr float kM = 524288.0f;   // BN count per channel

constexpr size_t kOffIdx   = 196608;
constexpr size_t kOffStats = 2293760;
constexpr size_t kOffScsh  = 2295808;
constexpr size_t kOffFlags = 2297856;                        // int[32]
constexpr size_t kOffU     = 2297984;
constexpr size_t kOffPmax  = kOffU + 16777216;               // 19075200
constexpr size_t kOffPmin  = kOffPmax + 8388608;
constexpr size_t kOffY1    = kOffPmin + 8388608;
constexpr size_t kWsNeedF  = kOffY1 + (size_t)kPT * 64 * 2;  // 102961280

constexpr int kLdsK = 72;  // bf16 row stride: 144 B (16B-aligned, 2-way banks)

using bf16x8 = __attribute__((ext_vector_type(8))) short;
using f32x4  = __attribute__((ext_vector_type(4))) float;
using u64 = unsigned long long;
}

__device__ __forceinline__ unsigned short f2bf(float f) {
  unsigned u = __float_as_uint(f);
  u += 0x7fffu + ((u >> 16) & 1u);
  return (unsigned short)(u >> 16);
}
__device__ __forceinline__ unsigned pack2bf(float a, float b) {
  return (unsigned)f2bf(a) | ((unsigned)f2bf(b) << 16);
}

__device__ __forceinline__ u64 kmax(u64 a, u64 b) { return a > b ? a : b; }

// DPP u64 max step (VALU-speed). Canonical 64-lane reduce chain:
// row_shr 1/2/4/8 (mask 0xf), row_bcast15 (mask 0xa), row_bcast31 (mask 0xc);
// full reduction lands in lane 63. bound_ctrl=false keeps old on unwritten
// lanes; hi/lo use identical ctrl so the pair stays consistent.
template <int CTRL, int RM>
__device__ __forceinline__ u64 kmax_dpp(u64 x) {
  const unsigned hi = (unsigned)(x >> 32), lo = (unsigned)x;
  const unsigned h2 = (unsigned)__builtin_amdgcn_update_dpp((int)hi, (int)hi, CTRL, RM, 0xf, false);
  const unsigned l2 = (unsigned)__builtin_amdgcn_update_dpp((int)lo, (int)lo, CTRL, RM, 0xf, false);
  const u64 y = ((u64)h2 << 32) | l2;
  return x > y ? x : y;
}

// ---------------------------------------------------------------- FPS ----
// 4 waves, 16 contiguous pts/lane in registers. rn-exact dist update; argmax
// via packed u64 key = (bits(d)<<32)|(~idx): d>=0 so bits monotone; max key
// = max value with first-occurrence (min index) tie-break. Single DPP chain,
// lane 63 writes the wave slot, u64 LDS merge. Publishes progress flags.
__device__ void fps_body(const float* __restrict__ x, float* __restrict__ new_xyz,
                         int* __restrict__ flags, int b, int tid, char* smem) {
  __builtin_amdgcn_s_setprio(3);  // keep fps waves favored vs shadow work
  float* xs = (float*)smem;
  float* ys = xs + kN;
  float* zs = ys + kN;
  u64* pvu = (u64*)(smem + 49152);  // [2][4] parity-buffered wave keys
  const int lane = tid & 63;
  const int wid = tid >> 6;
  const float* xb = x + (size_t)b * kN * 3;
  for (int q = tid; q < kN; q += 256) {
    xs[q] = xb[q * 3 + 0];
    ys[q] = xb[q * 3 + 1];
    zs[q] = xb[q * 3 + 2];
  }
  __syncthreads();
  float px[16], py[16], pz[16], dm[16];
  unsigned invc[16];
#pragma unroll
  for (int j = 0; j < 16; ++j) {
    const int p = tid * 16 + j;
    px[j] = xs[p]; py[j] = ys[p]; pz[j] = zs[p];
    dm[j] = 1e10f;
    invc[j] = 0xffffffffu - (unsigned)p;
  }
  int far = 0;
  for (int i = 0; i < kS; ++i) {
    const float cx = xs[far], cy = ys[far], cz = zs[far];
    if (tid == 0) {
      float* o = new_xyz + ((size_t)b * kS + i) * 3;
      o[0] = cx; o[1] = cy; o[2] = cz;
      if ((i & 15) == 15)  // batched publish: centroids [0..i] stored
        __hip_atomic_store(&flags[b], i + 1, __ATOMIC_RELEASE,
                           __HIP_MEMORY_SCOPE_AGENT);
    }
#pragma unroll
    for (int j = 0; j < 16; ++j) {
      const float dx = __fsub_rn(px[j], cx);
      const float dy = __fsub_rn(py[j], cy);
      const float dz = __fsub_rn(pz[j], cz);
      const float t = __fadd_rn(__fadd_rn(__fmul_rn(dx, dx), __fmul_rn(dy, dy)),
                                __fmul_rn(dz, dz));
      dm[j] = fminf(dm[j], t);
    }
    u64 k[16];
#pragma unroll
    for (int j = 0; j < 16; ++j)
      k[j] = ((u64)__float_as_uint(dm[j]) << 32) | invc[j];
    u64 t8[8], t4[4], t2[2];
#pragma unroll
    for (int j = 0; j < 8; ++j) t8[j] = kmax(k[j], k[j + 8]);
#pragma unroll
    for (int j = 0; j < 4; ++j) t4[j] = kmax(t8[j], t8[j + 4]);
#pragma unroll
    for (int j = 0; j < 2; ++j) t2[j] = kmax(t4[j], t4[j + 2]);
    u64 v = kmax(t2[0], t2[1]);
    v = kmax_dpp<0x111, 0xf>(v);
    v = kmax_dpp<0x112, 0xf>(v);
    v = kmax_dpp<0x114, 0xf>(v);
    v = kmax_dpp<0x118, 0xf>(v);
    v = kmax_dpp<0x142, 0xa>(v);
    v = kmax_dpp<0x143, 0xc>(v);
    const int par = i & 1;
    if (lane == 63) pvu[par * 4 + wid] = v;  // lane 63 holds full reduce
    __syncthreads();
    const u64 mm = kmax(kmax(pvu[par * 4 + 0], pvu[par * 4 + 1]),
                        kmax(pvu[par * 4 + 2], pvu[par * 4 + 3]));
    far = (int)(0xffffffffu - (unsigned)mm);
  }
}

// --------------------------------------------- U = feat . W0[:,3:]^T ----
__device__ void u_body(const float* __restrict__ xc, const float* __restrict__ W0,
                       float* __restrict__ U, int* __restrict__ flags,
                       int ublk, int tid, char* smem) {
  unsigned short* a_lds = (unsigned short*)smem;                       // [128][72]
  unsigned short* w_lds = (unsigned short*)(smem + 128 * kLdsK * 2);   // [64][72]
  const int r0 = ublk * 128;
  {
    const int pt = tid >> 1, half = tid & 1;
    const float4* src = (const float4*)(xc + ((size_t)(r0 + pt)) * 64 + half * 32);
    unsigned* dst = (unsigned*)(a_lds + pt * kLdsK + half * 32);
#pragma unroll
    for (int i = 0; i < 8; ++i) {
      const float4 v = src[i];
      dst[2 * i + 0] = pack2bf(v.x, v.y);
      dst[2 * i + 1] = pack2bf(v.z, v.w);
    }
  }
  for (int e = tid; e < 64 * 64; e += 256) {
    const int d = e >> 6, k2 = e & 63;
    w_lds[d * kLdsK + k2] = f2bf(W0[d * kCF + 3 + k2]);
  }
  __syncthreads();
  const int w = tid >> 6, lane = tid & 63, lr = lane & 15, lk = lane >> 4;
  f32x4 acc[2][4];
#pragma unroll
  for (int mi = 0; mi < 2; ++mi)
#pragma unroll
    for (int ni = 0; ni < 4; ++ni) acc[mi][ni] = (f32x4){0.f, 0.f, 0.f, 0.f};
#pragma unroll
  for (int ks = 0; ks < 2; ++ks) {
    const int k = lk * 8 + ks * 32;
    const bf16x8 a0 = *(const bf16x8*)(a_lds + (32 * w + lr) * kLdsK + k);
    const bf16x8 a1 = *(const bf16x8*)(a_lds + (32 * w + 16 + lr) * kLdsK + k);
#pragma unroll
    for (int ni = 0; ni < 4; ++ni) {
      const bf16x8 bv = *(const bf16x8*)(w_lds + (16 * ni + lr) * kLdsK + k);
      acc[0][ni] = __builtin_amdgcn_mfma_f32_16x16x32_bf16(a0, bv, acc[0][ni], 0, 0, 0);
      acc[1][ni] = __builtin_amdgcn_mfma_f32_16x16x32_bf16(a1, bv, acc[1][ni], 0, 0, 0);
    }
  }
#pragma unroll
  for (int mi = 0; mi < 2; ++mi)
#pragma unroll
    for (int ni = 0; ni < 4; ++ni)
#pragma unroll
      for (int r = 0; r < 4; ++r) {
        const int row = 32 * w + 16 * mi + lk * 4 + r;
        U[((size_t)(r0 + row)) * 64 + 16 * ni + lr] = acc[mi][ni][r];
      }
  __syncthreads();  // all U stores of this block issued & drained by barrier
  if (tid == 0)     // release (wbl2) makes them visible cross-XCD
    __hip_atomic_fetch_add(&flags[16], 1, __ATOMIC_RELEASE,
                           __HIP_MEMORY_SCOPE_AGENT);
}

// ------------------- fused ball query + stats0 (fps-shadow) --------------
// 224 persistent blocks (896 waves); wave W handles centroids W, W+896, ...
// Spins on flags[b] (fps progress) and flags[16] (U done). All co-resident
// by capacity: 752 blocks <= 3/CU * 256 (LDS- and launch_bounds-enforced).
__device__ void ballq_stats_body(const float* __restrict__ x,
                                 const float* __restrict__ nxyz,
                                 int* __restrict__ idx,
                                 const float* __restrict__ U,
                                 const float* __restrict__ W0,
                                 const float* __restrict__ b0,
                                 float* __restrict__ stats,
                                 int* __restrict__ flags,
                                 int blk, int tid, char* smem) {
  float* red = (float*)smem;             // [128]
  float4* w0c = (float4*)(smem + 512);   // [64]
  if (tid < 128) red[tid] = 0.0f;
  if (tid < 64) w0c[tid] = make_float4(W0[tid * kCF + 0], W0[tid * kCF + 1],
                                       W0[tid * kCF + 2], b0[tid]);
  __syncthreads();
  const int wid = tid >> 6, lane = tid & 63;
  const int W = blk * 4 + wid;  // [0, 896)
  while (__hip_atomic_load(&flags[16], __ATOMIC_RELAXED,
                           __HIP_MEMORY_SCOPE_AGENT) < 512)
    __builtin_amdgcn_s_sleep(32);
  (void)__hip_atomic_load(&flags[16], __ATOMIC_ACQUIRE, __HIP_MEMORY_SCOPE_AGENT);
  const float RR = (float)(0.2 * 0.2);
  const int half = lane & 1;
  float s_acc[32], q_acc[32];
#pragma unroll
  for (int i = 0; i < 32; ++i) { s_acc[i] = 0.f; q_acc[i] = 0.f; }
  for (int g = W; g < kB * kS; g += 896) {
    const int b = g >> 10;
    const int s = g & 1023;
    while (__hip_atomic_load(&flags[b], __ATOMIC_RELAXED,
                             __HIP_MEMORY_SCOPE_AGENT) <= s)
      __builtin_amdgcn_s_sleep(32);
    (void)__hip_atomic_load(&flags[b], __ATOMIC_ACQUIRE, __HIP_MEMORY_SCOPE_AGENT);
    const float nx = nxyz[g * 3 + 0];
    const float ny = nxyz[g * 3 + 1];
    const float nz = nxyz[g * 3 + 2];
    const float* xb = x + (size_t)b * kN * 3;
    int cnt = 0, first = -1;
    for (int c = 0; c < kN / 64 && cnt < kK; ++c) {
      const int p = c * 64 + lane;
      const float dx = __fsub_rn(xb[p * 3 + 0], nx);
      const float dy = __fsub_rn(xb[p * 3 + 1], ny);
      const float dz = __fsub_rn(xb[p * 3 + 2], nz);
      const float t = __fadd_rn(__fadd_rn(__fmul_rn(dx, dx), __fmul_rn(dy, dy)),
                                __fmul_rn(dz, dz));
      const bool within = (t <= RR);
      const unsigned long long m = __ballot(within);
      if (first < 0 && m != 0ull) first = c * 64 + __builtin_ctzll(m);
      const int pos = cnt + (int)__popcll(m & ((1ull << lane) - 1ull));
      if (within && pos < kK) idx[(size_t)g * kK + pos] = p;
      cnt += (int)__popcll(m);
    }
    for (int k2 = cnt + lane; k2 < kK; k2 += 64) idx[(size_t)g * kK + k2] = first;
    // stats0 for this centroid's 32 slots (2 lanes/point, 32 ch each)
    const int v = idx[(size_t)g * kK + (lane >> 1)];
    const float* xp = x + ((size_t)b * kN + v) * 3;
    const float rx = xp[0] - nx, ry = xp[1] - ny, rz = xp[2] - nz;
    const float4* up = (const float4*)(U + ((size_t)b * kN + v) * 64 + half * 32);
#pragma unroll
    for (int i = 0; i < 8; ++i) {
      const float4 u4 = up[i];
      const float uu[4] = {u4.x, u4.y, u4.z, u4.w};
#pragma unroll
      for (int j = 0; j < 4; ++j) {
        const float4 wc = w0c[half * 32 + i * 4 + j];
        const float y = uu[j] + rx * wc.x + ry * wc.y + rz * wc.z + wc.w;
        s_acc[i * 4 + j] += y;
        q_acc[i * 4 + j] += y * y;
      }
    }
  }
#pragma unroll
  for (int i = 0; i < 32; ++i) {
    atomicAdd(&red[half * 32 + i], s_acc[i]);
    atomicAdd(&red[64 + half * 32 + i], q_acc[i]);
  }
  __syncthreads();
  if (tid < 128) atomicAdd(&stats[tid], red[tid]);
}

// launch_bounds(256,3): cap VGPR so 3 blocks/CU -> 768 slots >= 752 blocks
// (co-residency = spin-safety by arithmetic, not dispatch order).
__global__ __launch_bounds__(256, 3) void k1_kernel(
    const float* __restrict__ x, const float* __restrict__ xc,
    const float* __restrict__ W0, const float* __restrict__ b0,
    float* __restrict__ nxyz, float* __restrict__ U, int* __restrict__ idx,
    float* __restrict__ stats, int* __restrict__ flags) {
  __shared__ __align__(16) char smem[49664];
  if (blockIdx.x < 16)
    fps_body(x, nxyz, flags, blockIdx.x, threadIdx.x, smem);
  else if (blockIdx.x < 528)
    u_body(xc, W0, U, flags, blockIdx.x - 16, threadIdx.x, smem);
  else
    ballq_stats_body(x, nxyz, idx, U, W0, b0, stats, flags,
                     blockIdx.x - 528, threadIdx.x, smem);
}

// ------------------------------------------------------------ finalize ----
__global__ void finalize_kernel(const float* __restrict__ g, const float* __restrict__ be,
                                const float* __restrict__ st, float* __restrict__ sc,
                                float* __restrict__ sh, int C) {
  const int c = threadIdx.x;
  if (c < C) {
    const float mean = st[c] / kM;
    const float var = st[C + c] / kM - mean * mean;
    const float scale = g[c] / sqrtf(var + 1e-5f);
    sc[c] = scale;
    sh[c] = be[c] - mean * scale;
  }
}

// =================== FULL PATH: A (stats1 + y1 store) ======================
__global__ __launch_bounds__(256) void mlpA_kernel(
    const float* __restrict__ x, const float* __restrict__ nxyz,
    const int* __restrict__ idx, const float* __restrict__ U,
    const float* __restrict__ W0, const float* __restrict__ b0,
    const float* __restrict__ W1, const float* __restrict__ b1v,
    const float* __restrict__ scsh, float* __restrict__ stats,
    unsigned short* __restrict__ y1out) {
  __shared__ unsigned short a_lds[128 * kLdsK];
  __shared__ unsigned short w_lds[64 * kLdsK];
  __shared__ float red[128];
  __shared__ float4 w0c[64];
  __shared__ float2 sc0l[64];
  const int tid = threadIdx.x;
  const int p0 = blockIdx.x * 128;
  if (tid < 128) red[tid] = 0.0f;
  if (tid < 64) {
    w0c[tid] = make_float4(W0[tid * kCF + 0], W0[tid * kCF + 1],
                           W0[tid * kCF + 2], b0[tid]);
    sc0l[tid] = make_float2(scsh[tid], scsh[64 + tid]);
  }
  for (int f = tid; f < 64 * 16; f += 256) {  // W1 bf16
    const int d = f >> 4, k4 = (f & 15) * 4;
    const float4 vw = *(const float4*)(W1 + d * 64 + k4);
    unsigned* dst = (unsigned*)(w_lds + d * kLdsK + k4);
    dst[0] = pack2bf(vw.x, vw.y);
    dst[1] = pack2bf(vw.z, vw.w);
  }
  __syncthreads();
  {  // gather + y0 + bn0 + relu -> a_lds (bf16)
    const int pt = tid >> 1, half = tid & 1;
    const int pg = p0 + pt;
    const int v = idx[pg];
    const int b = pg >> 15;
    const int sct = (pg & (kSK - 1)) >> 5;
    const float* xp = x + ((size_t)b * kN + v) * 3;
    const float* np = nxyz + ((size_t)b * kS + sct) * 3;
    const float rx = xp[0] - np[0], ry = xp[1] - np[1], rz = xp[2] - np[2];
    const float4* up = (const float4*)(U + ((size_t)b * kN + v) * 64 + half * 32);
    unsigned* dst = (unsigned*)(a_lds + pt * kLdsK + half * 32);
#pragma unroll
    for (int i = 0; i < 8; ++i) {
      const float4 u4 = up[i];
      const float uu[4] = {u4.x, u4.y, u4.z, u4.w};
      float a1[4];
#pragma unroll
      for (int j = 0; j < 4; ++j) {
        const int c = half * 32 + i * 4 + j;
        const float4 wc = w0c[c];
        const float y = uu[j] + rx * wc.x + ry * wc.y + rz * wc.z + wc.w;
        const float2 ss = sc0l[c];
        a1[j] = fmaxf(fmaf(y, ss.x, ss.y), 0.0f);
      }
      dst[2 * i + 0] = pack2bf(a1[0], a1[1]);
      dst[2 * i + 1] = pack2bf(a1[2], a1[3]);
    }
  }
  __syncthreads();

  const int w = tid >> 6, lane = tid & 63, lr = lane & 15, lk = lane >> 4;
  f32x4 acc1[2][4];
#pragma unroll
  for (int mi = 0; mi < 2; ++mi)
#pragma unroll
    for (int ni = 0; ni < 4; ++ni) acc1[mi][ni] = (f32x4){0.f, 0.f, 0.f, 0.f};
#pragma unroll
  for (int ks = 0; ks < 2; ++ks) {
    const int k = lk * 8 + ks * 32;
    const bf16x8 a0 = *(const bf16x8*)(a_lds + (32 * w + lr) * kLdsK + k);
    const bf16x8 a1 = *(const bf16x8*)(a_lds + (32 * w + 16 + lr) * kLdsK + k);
#pragma unroll
    for (int ni = 0; ni < 4; ++ni) {
      const bf16x8 bv = *(const bf16x8*)(w_lds + (16 * ni + lr) * kLdsK + k);
      acc1[0][ni] = __builtin_amdgcn_mfma_f32_16x16x32_bf16(a0, bv, acc1[0][ni], 0, 0, 0);
      acc1[1][ni] = __builtin_amdgcn_mfma_f32_16x16x32_bf16(a1, bv, acc1[1][ni], 0, 0, 0);
    }
  }
#pragma unroll
  for (int ni = 0; ni < 4; ++ni) {
    const int ch = 16 * ni + lr;
    const float bb = b1v[ch];
    float ss = 0.f, qq = 0.f;
#pragma unroll
    for (int mi = 0; mi < 2; ++mi)
#pragma unroll
      for (int r = 0; r < 4; ++r) {
        const float y = acc1[mi][ni][r] + bb;
        ss += y;
        qq += y * y;
        const int row = 32 * w + 16 * mi + lk * 4 + r;
        a_lds[row * kLdsK + ch] = f2bf(y);
      }
    atomicAdd(&red[ch], ss);
    atomicAdd(&red[64 + ch], qq);
  }
  __syncthreads();
  {  // coalesced y1 store
    const int row = tid >> 1, hf = tid & 1;
    const uint4* s4 = (const uint4*)(a_lds + row * kLdsK + hf * 32);
    uint4* d4 = (uint4*)(y1out + (size_t)(p0 + row) * 64 + hf * 32);
    d4[0] = s4[0]; d4[1] = s4[1]; d4[2] = s4[2]; d4[3] = s4[3];
  }
  if (tid < 128) atomicAdd(&stats[128 + tid], red[tid]);
}

// ============ FULL PATH: B (stats2 + pre-BN K-pool max/min) ================
__global__ __launch_bounds__(256) void mlpB_kernel(
    const unsigned short* __restrict__ y1in, const float* __restrict__ W2,
    const float* __restrict__ b2v, const float* __restrict__ scsh,
    float* __restrict__ stats, float* __restrict__ pmax,
    float* __restrict__ pmin) {
  __shared__ unsigned short a_lds[128 * kLdsK];
  __shared__ unsigned short w_lds[128 * kLdsK];
  __shared__ float red[256];
  __shared__ float2 s1l[64];
  const int tid = threadIdx.x;
  const int p0 = blockIdx.x * 128;
  red[tid] = 0.0f;
  if (tid < 64) s1l[tid] = make_float2(scsh[128 + tid], scsh[192 + tid]);
  __syncthreads();
  for (int f = tid; f < 128 * 16; f += 256) {  // W2 bf16
    const int d = f >> 4, k4 = (f & 15) * 4;
    const float4 vw = *(const float4*)(W2 + d * 64 + k4);
    unsigned* dst = (unsigned*)(w_lds + d * kLdsK + k4);
    dst[0] = pack2bf(vw.x, vw.y);
    dst[1] = pack2bf(vw.z, vw.w);
  }
  {  // y1 -> bn1 + relu -> a_lds (bf16)
    const int row = tid >> 1, hf = tid & 1;
    const uint4* src = (const uint4*)(y1in + (size_t)(p0 + row) * 64 + hf * 32);
    const uint4 qa = src[0], qb = src[1], qc = src[2], qd = src[3];
    const unsigned in[16] = {qa.x, qa.y, qa.z, qa.w, qb.x, qb.y, qb.z, qb.w,
                             qc.x, qc.y, qc.z, qc.w, qd.x, qd.y, qd.z, qd.w};
    unsigned* dst = (unsigned*)(a_lds + row * kLdsK) + hf * 16;
#pragma unroll
    for (int i2 = 0; i2 < 16; ++i2) {
      const unsigned u = in[i2];
      const int ch0 = hf * 32 + i2 * 2;
      const float2 sA = s1l[ch0];
      const float2 sB = s1l[ch0 + 1];
      const float flo = __uint_as_float(u << 16);
      const float fhi = __uint_as_float(u & 0xffff0000u);
      const float alo = fmaxf(fmaf(flo, sA.x, sA.y), 0.0f);
      const float ahi = fmaxf(fmaf(fhi, sB.x, sB.y), 0.0f);
      dst[i2] = pack2bf(alo, ahi);
    }
  }
  __syncthreads();

  const int w = tid >> 6, lane = tid & 63, lr = lane & 15, lk = lane >> 4;
  f32x4 acc2[2][8];
#pragma unroll
  for (int mi = 0; mi < 2; ++mi)
#pragma unroll
    for (int ni = 0; ni < 8; ++ni) acc2[mi][ni] = (f32x4){0.f, 0.f, 0.f, 0.f};
#pragma unroll
  for (int ks = 0; ks < 2; ++ks) {
    const int k = lk * 8 + ks * 32;
    const bf16x8 a0 = *(const bf16x8*)(a_lds + (32 * w + lr) * kLdsK + k);
    const bf16x8 a1 = *(const bf16x8*)(a_lds + (32 * w + 16 + lr) * kLdsK + k);
#pragma unroll
    for (int ni = 0; ni < 8; ++ni) {
      const bf16x8 bv = *(const bf16x8*)(w_lds + (16 * ni + lr) * kLdsK + k);
      acc2[0][ni] = __builtin_amdgcn_mfma_f32_16x16x32_bf16(a0, bv, acc2[0][ni], 0, 0, 0);
      acc2[1][ni] = __builtin_amdgcn_mfma_f32_16x16x32_bf16(a1, bv, acc2[1][ni], 0, 0, 0);
    }
  }
  float mxv[8], mnv[8];
#pragma unroll
  for (int ni = 0; ni < 8; ++ni) {
    const int ch = 16 * ni + lr;
    const float bb = b2v[ch];
    float ss = 0.f, qq = 0.f;
    float mx = -3.4e38f, mn = 3.4e38f;
#pragma unroll
    for (int mi = 0; mi < 2; ++mi)
#pragma unroll
      for (int r = 0; r < 4; ++r) {
        const float a = acc2[mi][ni][r];
        const float y = a + bb;
        ss += y;
        qq += y * y;
        mx = fmaxf(mx, a);
        mn = fminf(mn, a);
      }
    atomicAdd(&red[ch], ss);
    atomicAdd(&red[128 + ch], qq);
    mx = fmaxf(mx, __shfl_xor(mx, 16, 64));
    mx = fmaxf(mx, __shfl_xor(mx, 32, 64));
    mn = fminf(mn, __shfl_xor(mn, 16, 64));
    mn = fminf(mn, __shfl_xor(mn, 32, 64));
    mxv[ni] = mx + bb;
    mnv[ni] = mn + bb;
  }
  __syncthreads();
  atomicAdd(&stats[256 + tid], red[tid]);
  const int pg0 = p0 + 32 * w;
  const int ob = pg0 >> 15;
  const int os = (pg0 & (kSK - 1)) >> 5;
  if (lane < 16) {
#pragma unroll
    for (int ni = 0; ni < 8; ++ni) {
      const size_t off = ((size_t)ob * 128 + 16 * ni + lane) * kS + os;
      pmax[off] = mxv[ni];
      pmin[off] = mnv[ni];
    }
  }
}

// ============ FULL PATH: C (bn2+relu on pooled values; monotone) ===========
__global__ __launch_bounds__(256) void poolbn_kernel(
    const float* __restrict__ pmax, const float* __restrict__ pmin,
    const float* __restrict__ scsh, float* __restrict__ out) {
  const int gid = blockIdx.x * 256 + threadIdx.x;
  const int c = (gid >> 10) & 127;
  const float sc = scsh[256 + c];
  const float sh = scsh[384 + c];
  const float p = (sc >= 0.f) ? pmax[gid] : pmin[gid];
  out[gid] = fmaxf(fmaf(p, sc, sh), 0.0f);
}

// =================== FALLBACK (ws < full): r5 mlp path =====================
template <int STAGE>
__global__ __launch_bounds__(256) void mlp_kernel(
    const float* __restrict__ x, const float* __restrict__ nxyz,
    const int* __restrict__ idx, const float* __restrict__ U,
    const float* __restrict__ W0, const float* __restrict__ b0,
    const float* __restrict__ W1, const float* __restrict__ b1v,
    const float* __restrict__ W2, const float* __restrict__ b2v,
    const float* __restrict__ scsh, float* __restrict__ stats,
    float* __restrict__ out) {
  __shared__ unsigned short a_lds[128 * kLdsK];
  __shared__ unsigned short w_lds[128 * kLdsK];
  __shared__ float red[256];
  __shared__ float4 w0c[64];
  __shared__ float2 sc0l[64];
  const int tid = threadIdx.x;
  const int p0 = blockIdx.x * 128;
  red[tid] = 0.0f;
  if (tid < 64) {
    w0c[tid] = make_float4(W0[tid * kCF + 0], W0[tid * kCF + 1],
                           W0[tid * kCF + 2], b0[tid]);
    sc0l[tid] = make_float2(scsh[tid], scsh[64 + tid]);
  }
  for (int f = tid; f < 64 * 16; f += 256) {
    const int d = f >> 4, k4 = (f & 15) * 4;
    const float4 vw = *(const float4*)(W1 + d * 64 + k4);
    unsigned* dst = (unsigned*)(w_lds + d * kLdsK + k4);
    dst[0] = pack2bf(vw.x, vw.y);
    dst[1] = pack2bf(vw.z, vw.w);
  }
  __syncthreads();
  {
    const int pt = tid >> 1, half = tid & 1;
    const int pg = p0 + pt;
    const int v = idx[pg];
    const int b = pg >> 15;
    const int sct = (pg & (kSK - 1)) >> 5;
    const float* xp = x + ((size_t)b * kN + v) * 3;
    const float* np = nxyz + ((size_t)b * kS + sct) * 3;
    const float rx = xp[0] - np[0], ry = xp[1] - np[1], rz = xp[2] - np[2];
    const float4* up = (const float4*)(U + ((size_t)b * kN + v) * 64 + half * 32);
    unsigned* dst = (unsigned*)(a_lds + pt * kLdsK + half * 32);
#pragma unroll
    for (int i = 0; i < 8; ++i) {
      const float4 u4 = up[i];
      const float uu[4] = {u4.x, u4.y, u4.z, u4.w};
      float a1[4];
#pragma unroll
      for (int j = 0; j < 4; ++j) {
        const int c = half * 32 + i * 4 + j;
        const float4 wc = w0c[c];
        const float y = uu[j] + rx * wc.x + ry * wc.y + rz * wc.z + wc.w;
        const float2 ss = sc0l[c];
        a1[j] = fmaxf(fmaf(y, ss.x, ss.y), 0.0f);
      }
      dst[2 * i + 0] = pack2bf(a1[0], a1[1]);
      dst[2 * i + 1] = pack2bf(a1[2], a1[3]);
    }
  }
  __syncthreads();

  const int w = tid >> 6, lane = tid & 63, lr = lane & 15, lk = lane >> 4;
  f32x4 acc1[2][4];
#pragma unroll
  for (int mi = 0; mi < 2; ++mi)
#pragma unroll
    for (int ni = 0; ni < 4; ++ni) acc1[mi][ni] = (f32x4){0.f, 0.f, 0.f, 0.f};
#pragma unroll
  for (int ks = 0; ks < 2; ++ks) {
    const int k = lk * 8 + ks * 32;
    const bf16x8 a0 = *(const bf16x8*)(a_lds + (32 * w + lr) * kLdsK + k);
    const bf16x8 a1 = *(const bf16x8*)(a_lds + (32 * w + 16 + lr) * kLdsK + k);
#pragma unroll
    for (int ni = 0; ni < 4; ++ni) {
      const bf16x8 bv = *(const bf16x8*)(w_lds + (16 * ni + lr) * kLdsK + k);
      acc1[0][ni] = __builtin_amdgcn_mfma_f32_16x16x32_bf16(a0, bv, acc1[0][ni], 0, 0, 0);
      acc1[1][ni] = __builtin_amdgcn_mfma_f32_16x16x32_bf16(a1, bv, acc1[1][ni], 0, 0, 0);
    }
  }

  if constexpr (STAGE == 1) {
#pragma unroll
    for (int ni = 0; ni < 4; ++ni) {
      const int ch = 16 * ni + lr;
      const float bb = b1v[ch];
      float ss = 0.f, qq = 0.f;
#pragma unroll
      for (int mi = 0; mi < 2; ++mi)
#pragma unroll
        for (int r = 0; r < 4; ++r) {
          const float y = acc1[mi][ni][r] + bb;
          ss += y;
          qq += y * y;
        }
      atomicAdd(&red[ch], ss);
      atomicAdd(&red[64 + ch], qq);
    }
    __syncthreads();
    if (tid < 128) atomicAdd(&stats[128 + tid], red[tid]);
    return;
  } else {
    __syncthreads();
#pragma unroll
    for (int ni = 0; ni < 4; ++ni) {
      const int ch = 16 * ni + lr;
      const float bb = b1v[ch];
      const float sc1 = scsh[128 + ch], sh1 = scsh[192 + ch];
#pragma unroll
      for (int mi = 0; mi < 2; ++mi)
#pragma unroll
        for (int r = 0; r < 4; ++r) {
          const int row = 32 * w + 16 * mi + lk * 4 + r;
          const float val = fmaxf(fmaf(acc1[mi][ni][r] + bb, sc1, sh1), 0.0f);
          a_lds[row * kLdsK + ch] = f2bf(val);
        }
    }
    for (int f = tid; f < 128 * 16; f += 256) {
      const int d = f >> 4, k4 = (f & 15) * 4;
      const float4 vw = *(const float4*)(W2 + d * 64 + k4);
      unsigned* dst = (unsigned*)(w_lds + d * kLdsK + k4);
      dst[0] = pack2bf(vw.x, vw.y);
      dst[1] = pack2bf(vw.z, vw.w);
    }
    __syncthreads();

    f32x4 acc2[2][8];
#pragma unroll
    for (int mi = 0; mi < 2; ++mi)
#pragma unroll
      for (int ni = 0; ni < 8; ++ni) acc2[mi][ni] = (f32x4){0.f, 0.f, 0.f, 0.f};
#pragma unroll
    for (int ks = 0; ks < 2; ++ks) {
      const int k = lk * 8 + ks * 32;
      const bf16x8 a0 = *(const bf16x8*)(a_lds + (32 * w + lr) * kLdsK + k);
      const bf16x8 a1 = *(const bf16x8*)(a_lds + (32 * w + 16 + lr) * kLdsK + k);
#pragma unroll
      for (int ni = 0; ni < 8; ++ni) {
        const bf16x8 bv = *(const bf16x8*)(w_lds + (16 * ni + lr) * kLdsK + k);
        acc2[0][ni] = __builtin_amdgcn_mfma_f32_16x16x32_bf16(a0, bv, acc2[0][ni], 0, 0, 0);
        acc2[1][ni] = __builtin_amdgcn_mfma_f32_16x16x32_bf16(a1, bv, acc2[1][ni], 0, 0, 0);
      }
    }

    if constexpr (STAGE == 2) {
#pragma unroll
      for (int ni = 0; ni < 8; ++ni) {
        const int ch = 16 * ni + lr;
        const float bb = b2v[ch];
        float ss = 0.f, qq = 0.f;
#pragma unroll
        for (int mi = 0; mi < 2; ++mi)
#pragma unroll
          for (int r = 0; r < 4; ++r) {
            const float y = acc2[mi][ni][r] + bb;
            ss += y;
            qq += y * y;
          }
        atomicAdd(&red[ch], ss);
        atomicAdd(&red[128 + ch], qq);
      }
      __syncthreads();
      atomicAdd(&stats[256 + tid], red[tid]);
    } else {
      float mx[8];
#pragma unroll
      for (int ni = 0; ni < 8; ++ni) {
        const int ch = 16 * ni + lr;
        const float bb = b2v[ch];
        const float sc2 = scsh[256 + ch], sh2 = scsh[384 + ch];
        float m = -1.0f;
#pragma unroll
        for (int mi = 0; mi < 2; ++mi)
#pragma unroll
          for (int r = 0; r < 4; ++r)
            m = fmaxf(m, fmaxf(fmaf(acc2[mi][ni][r] + bb, sc2, sh2), 0.0f));
        mx[ni] = m;
      }
#pragma unroll
      for (int ni = 0; ni < 8; ++ni) {
        mx[ni] = fmaxf(mx[ni], __shfl_xor(mx[ni], 16, 64));
        mx[ni] = fmaxf(mx[ni], __shfl_xor(mx[ni], 32, 64));
      }
      const int pg0 = p0 + 32 * w;
      const int ob = pg0 >> 15;
      const int os = (pg0 & (kSK - 1)) >> 5;
      if (lane < 16) {
#pragma unroll
        for (int ni = 0; ni < 8; ++ni)
          out[((size_t)ob * 128 + 16 * ni + lane) * kS + os] = mx[ni];
      }
    }
  }
}

// --------------------------------------------------------------- launch ----
extern "C" void kernel_launch(void* const* d_in, const int* in_sizes, int n_in,
                              void* d_out, int out_size, void* d_ws, size_t ws_size,
                              hipStream_t stream) {
  const float* x   = (const float*)d_in[0];
  const float* xc  = (const float*)d_in[1];
  const float* W0  = (const float*)d_in[2];
  const float* b0  = (const float*)d_in[3];
  const float* g0  = (const float*)d_in[4];
  const float* be0 = (const float*)d_in[5];
  const float* W1  = (const float*)d_in[6];
  const float* b1  = (const float*)d_in[7];
  const float* g1  = (const float*)d_in[8];
  const float* be1 = (const float*)d_in[9];
  const float* W2  = (const float*)d_in[10];
  const float* b2  = (const float*)d_in[11];
  const float* g2  = (const float*)d_in[12];
  const float* be2 = (const float*)d_in[13];
  float* out = (float*)d_out;
  char* ws = (char*)d_ws;
  float* nxyz  = (float*)(ws);
  int*   idx   = (int*)(ws + kOffIdx);
  float* stats = (float*)(ws + kOffStats);
  float* scsh  = (float*)(ws + kOffScsh);
  int*   flags = (int*)(ws + kOffFlags);
  float* U     = (float*)(ws + kOffU);
  float* pmax  = (float*)(ws + kOffPmax);
  float* pmin  = (float*)(ws + kOffPmin);
  unsigned short* y1 = (unsigned short*)(ws + kOffY1);
  (void)in_sizes; (void)n_in; (void)out_size;

  // clears stats (2048B) + scsh (2048B, rewritten later) + flags (128B)
  hipMemsetAsync(stats, 0, 4224, stream);
  k1_kernel<<<16 + 512 + 224, 256, 0, stream>>>(x, xc, W0, b0, nxyz, U, idx,
                                                stats, flags);
  finalize_kernel<<<1, 128, 0, stream>>>(g0, be0, stats, scsh, scsh + 64, 64);

  if (ws_size >= kWsNeedF) {
    mlpA_kernel<<<kPT / 128, 256, 0, stream>>>(x, nxyz, idx, U, W0, b0, W1, b1,
                                               scsh, stats, y1);
    finalize_kernel<<<1, 128, 0, stream>>>(g1, be1, stats + 128, scsh + 128, scsh + 192, 64);
    mlpB_kernel<<<kPT / 128, 256, 0, stream>>>(y1, W2, b2, scsh, stats, pmax, pmin);
    finalize_kernel<<<1, 128, 0, stream>>>(g2, be2, stats + 256, scsh + 256, scsh + 384, 128);
    poolbn_kernel<<<(kB * 128 * kS) / 256, 256, 0, stream>>>(pmax, pmin, scsh, out);
  } else {
    mlp_kernel<1><<<kPT / 128, 256, 0, stream>>>(x, nxyz, idx, U, W0, b0, W1, b1,
                                                 W2, b2, scsh, stats, out);
    finalize_kernel<<<1, 128, 0, stream>>>(g1, be1, stats + 128, scsh + 128, scsh + 192, 64);
    mlp_kernel<2><<<kPT / 128, 256, 0, stream>>>(x, nxyz, idx, U, W0, b0, W1, b1,
                                                 W2, b2, scsh, stats, out);
    finalize_kernel<<<1, 128, 0, stream>>>(g2, be2, stats + 256, scsh + 256, scsh + 384, 128);
    mlp_kernel<3><<<kPT / 128, 256, 0, stream>>>(x, nxyz, idx, U, W0, b0, W1, b1,
                                                 W2, b2, scsh, stats, out);
  }
}